// Round 13
// baseline (390.976 us; speedup 1.0000x reference)
//
#include <hip/hip_runtime.h>
#include <math.h>

typedef unsigned short u16;
typedef __attribute__((ext_vector_type(8))) short bf16x8;   // 8 bf16 = 4 VGPRs
typedef __attribute__((ext_vector_type(4))) float f32x4;

__device__ __forceinline__ float b2f(u16 u) {
    union { unsigned int i; float f; } v; v.i = ((unsigned int)u) << 16; return v.f;
}
__device__ __forceinline__ u16 f2b(float f) {
    union { float f; unsigned int i; } v; v.f = f;
    unsigned int r = v.i + 0x7FFFu + ((v.i >> 16) & 1u);   // round-nearest-even
    return (u16)(r >> 16);
}
__device__ __forceinline__ float gelu_exact(float v) {
    return 0.5f * v * (1.0f + erff(v * 0.70710678118654752f));
}

// async global->LDS, 16 B per lane; LDS dest = wave-uniform base + lane*16
__device__ __forceinline__ void load_lds16(const u16* gp, u16* lp) {
    __builtin_amdgcn_global_load_lds(
        (const __attribute__((address_space(1))) void*)gp,
        (__attribute__((address_space(3))) void*)lp,
        16, 0, 0);
}

// ---------------------------------------------------------------------------
// Elementwise fp32 -> bf16 convert (x)
// ---------------------------------------------------------------------------
__global__ __launch_bounds__(256) void convert_f2b(const float* __restrict__ in,
                                                   u16* __restrict__ out) {
    const int idx = blockIdx.x * 256 + threadIdx.x;
    float4 v = ((const float4*)in)[idx];
    ushort4 u; u.x = f2b(v.x); u.y = f2b(v.y); u.z = f2b(v.z); u.w = f2b(v.w);
    ((ushort4*)out)[idx] = u;
}

// ---------------------------------------------------------------------------
// All three weight transposes in ONE dispatch. 32x32 LDS tiles.
// blocks [0,1024): Wk (1024x1024); [1024,5120): Wv (1024x4096);
// [5120,9216): Wf (4096x1024).
// ---------------------------------------------------------------------------
__global__ __launch_bounds__(256) void transpose_all(
    const float* __restrict__ Wk, const float* __restrict__ Wv,
    const float* __restrict__ Wf,
    u16* __restrict__ Wkt, u16* __restrict__ Wvt, u16* __restrict__ Wft)
{
    const int gid = blockIdx.x;
    const float* W; u16* Wt; int N, K, n0, k0;
    if (gid < 1024) {
        W = Wk; Wt = Wkt; N = 1024; K = 1024;
        n0 = (gid & 31) * 32; k0 = (gid >> 5) * 32;
    } else if (gid < 5120) {
        const int g = gid - 1024;
        W = Wv; Wt = Wvt; N = 4096; K = 1024;
        n0 = (g & 127) * 32; k0 = (g >> 7) * 32;
    } else {
        const int g = gid - 5120;
        W = Wf; Wt = Wft; N = 1024; K = 4096;
        n0 = (g & 31) * 32; k0 = (g >> 5) * 32;
    }
    __shared__ float t[32][33];
    const int tid = threadIdx.x;
    const int c = tid & 31, r = tid >> 5;   // 8 rows/pass
    #pragma unroll
    for (int p = 0; p < 4; p++)
        t[r + p * 8][c] = W[(size_t)(k0 + r + p * 8) * N + n0 + c];
    __syncthreads();
    #pragma unroll
    for (int p = 0; p < 4; p++)
        Wt[(size_t)(n0 + r + p * 8) * K + k0 + c] = f2b(t[c][r + p * 8]);
}

// ---------------------------------------------------------------------------
// Fused K+V projection GEMM, 128x128x64 tile. N-space = 5120:
// cols [0,1024)  -> K = x@Wk + bk, bf16 normal store to Kbuf[4096][1024]
// cols [1024,5120) -> V = x@Wv + bv, bf16 TRANSPOSED store to Vt[b][h][dv][s]
// ---------------------------------------------------------------------------
__global__ __launch_bounds__(256) void mfma_kv(
    const u16* __restrict__ A, const u16* __restrict__ Wkt,
    const u16* __restrict__ Wvt, const float* __restrict__ bk,
    const float* __restrict__ bv, u16* __restrict__ Kbuf,
    u16* __restrict__ Vt)
{
    const int K = 1024;
    __shared__ u16 As[128 * 64];   // 16 KB
    __shared__ u16 Bs[128 * 64];   // 16 KB

    const int tid = threadIdx.x;
    const int w = tid >> 6, lane = tid & 63;
    const int m16 = lane & 15, quad = lane >> 4;
    const int wm = w >> 1, wn = w & 1;
    const int row0 = blockIdx.y * 128;
    const int col0g = blockIdx.x * 128;
    const bool isK = (col0g < 1024);
    const u16* Bt = isK ? Wkt : Wvt;
    const int bcol0 = isK ? col0g : col0g - 1024;
    const float* bias = isK ? bk : bv;
    const int lr = lane >> 3, lc = lane & 7;
    const int sw8 = (lc ^ (lr & 7)) * 8;

    f32x4 acc[4][4];
    #pragma unroll
    for (int i = 0; i < 4; i++)
        #pragma unroll
        for (int j = 0; j < 4; j++) acc[i][j] = (f32x4){0.f, 0.f, 0.f, 0.f};

    for (int k0 = 0; k0 < K; k0 += 64) {
        __syncthreads();
        #pragma unroll
        for (int c2 = 0; c2 < 4; c2++)
            load_lds16(A + (size_t)(row0 + c2 * 32 + w * 8 + lr) * K + k0 + sw8,
                       &As[(c2 * 32 + w * 8) * 64]);
        #pragma unroll
        for (int c2 = 0; c2 < 4; c2++)
            load_lds16(Bt + (size_t)(bcol0 + c2 * 32 + w * 8 + lr) * K + k0 + sw8,
                       &Bs[(c2 * 32 + w * 8) * 64]);
        __syncthreads();

        bf16x8 af[4][2], bfr[4][2];
        #pragma unroll
        for (int mt = 0; mt < 4; mt++)
            #pragma unroll
            for (int ks = 0; ks < 2; ks++)
                af[mt][ks] = *(const bf16x8*)&As[(wm * 64 + mt * 16 + m16) * 64 +
                                                 (((ks * 4 + quad) ^ (m16 & 7)) * 8)];
        #pragma unroll
        for (int nt = 0; nt < 4; nt++)
            #pragma unroll
            for (int ks = 0; ks < 2; ks++)
                bfr[nt][ks] = *(const bf16x8*)&Bs[(wn * 64 + nt * 16 + m16) * 64 +
                                                  (((ks * 4 + quad) ^ (m16 & 7)) * 8)];

        #pragma unroll
        for (int ks = 0; ks < 2; ks++)
            #pragma unroll
            for (int mt = 0; mt < 4; mt++)
                #pragma unroll
                for (int nt = 0; nt < 4; nt++)
                    acc[mt][nt] = __builtin_amdgcn_mfma_f32_16x16x32_bf16(af[mt][ks], bfr[nt][ks], acc[mt][nt], 0, 0, 0);
    }

    if (isK) {
        #pragma unroll
        for (int mt = 0; mt < 4; mt++) {
            #pragma unroll
            for (int nt = 0; nt < 4; nt++) {
                const int c = bcol0 + wn * 64 + nt * 16 + m16;
                const float bc = bias[c];
                #pragma unroll
                for (int reg = 0; reg < 4; reg++) {
                    const int r = row0 + wm * 64 + mt * 16 + quad * 4 + reg;
                    Kbuf[(size_t)r * 1024 + c] = f2b(acc[mt][nt][reg] + bc);
                }
            }
        }
    } else {
        #pragma unroll
        for (int mt = 0; mt < 4; mt++) {
            const int r0 = row0 + wm * 64 + mt * 16 + quad * 4;
            const int bb = r0 >> 11, s = r0 & 2047;
            #pragma unroll
            for (int nt = 0; nt < 4; nt++) {
                const int c = bcol0 + wn * 64 + nt * 16 + m16;
                const int h = c >> 8, dv = c & 255;
                const float bc = bias[c];
                ushort4 w4;
                w4.x = f2b(acc[mt][nt][0] + bc);
                w4.y = f2b(acc[mt][nt][1] + bc);
                w4.z = f2b(acc[mt][nt][2] + bc);
                w4.w = f2b(acc[mt][nt][3] + bc);
                *(ushort4*)(Vt + (((size_t)((bb * 16 + h) * 256 + dv)) << 11) + s) = w4;
            }
        }
    }
}

// ---------------------------------------------------------------------------
// FFN GEMM, 128x128x64 tile: out = gelu_o @ Wft^T + bf + x (fp32 store)
// ---------------------------------------------------------------------------
__global__ __launch_bounds__(256) void mfma_ffn(
    const u16* __restrict__ A, const u16* __restrict__ Bt,
    const float* __restrict__ bias, const float* __restrict__ resid,
    float* __restrict__ C, int M, int N, int K)
{
    __shared__ u16 As[128 * 64];   // 16 KB
    __shared__ u16 Bs[128 * 64];   // 16 KB

    const int tid = threadIdx.x;
    const int w = tid >> 6, lane = tid & 63;
    const int m16 = lane & 15, quad = lane >> 4;
    const int wm = w >> 1, wn = w & 1;
    const int row0 = blockIdx.y * 128, col0 = blockIdx.x * 128;
    const int lr = lane >> 3, lc = lane & 7;
    const int sw8 = (lc ^ (lr & 7)) * 8;

    f32x4 acc[4][4];
    #pragma unroll
    for (int i = 0; i < 4; i++)
        #pragma unroll
        for (int j = 0; j < 4; j++) acc[i][j] = (f32x4){0.f, 0.f, 0.f, 0.f};

    for (int k0 = 0; k0 < K; k0 += 64) {
        __syncthreads();
        #pragma unroll
        for (int c2 = 0; c2 < 4; c2++)
            load_lds16(A + (size_t)(row0 + c2 * 32 + w * 8 + lr) * K + k0 + sw8,
                       &As[(c2 * 32 + w * 8) * 64]);
        #pragma unroll
        for (int c2 = 0; c2 < 4; c2++)
            load_lds16(Bt + (size_t)(col0 + c2 * 32 + w * 8 + lr) * K + k0 + sw8,
                       &Bs[(c2 * 32 + w * 8) * 64]);
        __syncthreads();

        bf16x8 af[4][2], bfr[4][2];
        #pragma unroll
        for (int mt = 0; mt < 4; mt++)
            #pragma unroll
            for (int ks = 0; ks < 2; ks++)
                af[mt][ks] = *(const bf16x8*)&As[(wm * 64 + mt * 16 + m16) * 64 +
                                                 (((ks * 4 + quad) ^ (m16 & 7)) * 8)];
        #pragma unroll
        for (int nt = 0; nt < 4; nt++)
            #pragma unroll
            for (int ks = 0; ks < 2; ks++)
                bfr[nt][ks] = *(const bf16x8*)&Bs[(wn * 64 + nt * 16 + m16) * 64 +
                                                  (((ks * 4 + quad) ^ (m16 & 7)) * 8)];

        #pragma unroll
        for (int ks = 0; ks < 2; ks++)
            #pragma unroll
            for (int mt = 0; mt < 4; mt++)
                #pragma unroll
                for (int nt = 0; nt < 4; nt++)
                    acc[mt][nt] = __builtin_amdgcn_mfma_f32_16x16x32_bf16(af[mt][ks], bfr[nt][ks], acc[mt][nt], 0, 0, 0);
    }

    #pragma unroll
    for (int mt = 0; mt < 4; mt++) {
        #pragma unroll
        for (int nt = 0; nt < 4; nt++) {
            const int c = col0 + wn * 64 + nt * 16 + m16;
            const float bc = bias[c];
            #pragma unroll
            for (int reg = 0; reg < 4; reg++) {
                const int r = row0 + wm * 64 + mt * 16 + quad * 4 + reg;
                C[(size_t)r * N + c] = acc[mt][nt][reg] + bc + resid[(size_t)r * N + c];
            }
        }
    }
}

// ---------------------------------------------------------------------------
// Flash-style causal attention (R12 structure, unchanged): q-split QK^T,
// dv-split PV, max-free softmax, fused exact GELU, reg-prefetch dbuf.
// ---------------------------------------------------------------------------
__global__ __launch_bounds__(256) void attn_kernel(
    const float* __restrict__ X,    // [B*S, 1024]
    const u16*  __restrict__ Kb,    // [B*S, 1024] bf16
    const u16*  __restrict__ Vt,    // [b][h][256][2048] bf16
    u16* __restrict__ O,            // [B*S, 4096] bf16 (gelu applied)
    int B, int S)
{
    const int DM = 1024, DH = 4096;
    __shared__ u16 Ks[64 * 64];    // 8 KB
    __shared__ u16 Ps[64 * 64];    // 8 KB
    __shared__ u16 Vts[256 * 64];  // 32 KB  (48 KB total)

    const int tid = threadIdx.x;
    const int w = tid >> 6, lane = tid & 63;
    const int m16 = lane & 15, quad = lane >> 4;
    const int lr = lane >> 3, lc = lane & 7;
    const int sw8 = (lc ^ (lr & 7)) * 8;
    const int b = blockIdx.z, h = blockIdx.y;
    const int qt = (S / 64 - 1) - blockIdx.x;   // big tiles first
    const int q0 = qt * 64;
    const size_t baseRow = (size_t)b * S;
    const size_t vhead = ((size_t)(b * 16 + h) * 256) << 11;

    bf16x8 aq[2];
    {
        const float* qsrc = X + (baseRow + q0 + w * 16 + m16) * DM + h * 64;
        #pragma unroll
        for (int ks = 0; ks < 2; ks++) {
            float4 v0 = *(const float4*)(qsrc + ks * 32 + quad * 8);
            float4 v1 = *(const float4*)(qsrc + ks * 32 + quad * 8 + 4);
            bf16x8 u;
            u[0] = (short)f2b(v0.x); u[1] = (short)f2b(v0.y); u[2] = (short)f2b(v0.z); u[3] = (short)f2b(v0.w);
            u[4] = (short)f2b(v1.x); u[5] = (short)f2b(v1.y); u[6] = (short)f2b(v1.z); u[7] = (short)f2b(v1.w);
            aq[ks] = u;
        }
    }

    f32x4 o_acc[4][4];
    #pragma unroll
    for (int i = 0; i < 4; i++)
        #pragma unroll
        for (int j = 0; j < 4; j++) o_acc[i][j] = (f32x4){0.f, 0.f, 0.f, 0.f};
    f32x4 lacc4[4];
    #pragma unroll
    for (int i = 0; i < 4; i++) lacc4[i] = (f32x4){0.f, 0.f, 0.f, 0.f};

    bf16x8 onesf;
    {
        const short one = (m16 == 0) ? (short)0x3F80 : (short)0;
        #pragma unroll
        for (int i = 0; i < 8; i++) onesf[i] = one;
    }

    bf16x8 kreg[2], vreg[8];
    #pragma unroll
    for (int p = 0; p < 2; p++)
        kreg[p] = *(const bf16x8*)(Kb + (baseRow + p * 32 + w * 8 + lr) * DM + h * 64 + sw8);
    #pragma unroll
    for (int p = 0; p < 8; p++)
        vreg[p] = *(const bf16x8*)(Vt + vhead + (((size_t)(p * 32 + w * 8 + lr)) << 11) + sw8);
    #pragma unroll
    for (int p = 0; p < 2; p++)
        *(bf16x8*)&Ks[(p * 32 + w * 8) * 64 + lane * 8] = kreg[p];
    #pragma unroll
    for (int p = 0; p < 8; p++)
        *(bf16x8*)&Vts[(p * 32 + w * 8) * 64 + lane * 8] = vreg[p];
    __syncthreads();

    const int nch = qt + 1;
    for (int ch = 0; ch < nch; ch++) {
        const int k0 = ch * 64;
        const bool more = (ch + 1 < nch);

        if (more) {
            const int kn = k0 + 64;
            #pragma unroll
            for (int p = 0; p < 2; p++)
                kreg[p] = *(const bf16x8*)(Kb + (baseRow + kn + p * 32 + w * 8 + lr) * DM + h * 64 + sw8);
            #pragma unroll
            for (int p = 0; p < 8; p++)
                vreg[p] = *(const bf16x8*)(Vt + vhead + (((size_t)(p * 32 + w * 8 + lr)) << 11) + kn + sw8);
        }

        const int qg = q0 + w * 16 + quad * 4;
        #pragma unroll
        for (int nt = 0; nt < 4; nt++) {
            f32x4 acc = (f32x4){0.f, 0.f, 0.f, 0.f};
            #pragma unroll
            for (int ks = 0; ks < 2; ks++) {
                bf16x8 bk8 = *(const bf16x8*)&Ks[(nt * 16 + m16) * 64 + (((ks * 4 + quad) ^ (m16 & 7)) * 8)];
                acc = __builtin_amdgcn_mfma_f32_16x16x32_bf16(aq[ks], bk8, acc, 0, 0, 0);
            }
            const int kg = k0 + nt * 16 + m16;
            #pragma unroll
            for (int reg = 0; reg < 4; reg++) {
                const float p = (kg <= qg + reg) ? __expf(acc[reg] - 20.f) : 0.f;
                const int srow = w * 16 + quad * 4 + reg;
                Ps[srow * 64 + (((nt * 2 + (m16 >> 3)) ^ (srow & 7)) * 8) + (m16 & 7)] = f2b(p);
            }
        }
        __syncthreads();   // b1: Ps visible; Ks reads done

        if (more) {
            #pragma unroll
            for (int p = 0; p < 2; p++)
                *(bf16x8*)&Ks[(p * 32 + w * 8) * 64 + lane * 8] = kreg[p];
        }

        #pragma unroll
        for (int mt = 0; mt < 4; mt++) {
            bf16x8 pa0 = *(const bf16x8*)&Ps[(mt * 16 + m16) * 64 + (((0 + quad) ^ (m16 & 7)) * 8)];
            bf16x8 pa1 = *(const bf16x8*)&Ps[(mt * 16 + m16) * 64 + (((4 + quad) ^ (m16 & 7)) * 8)];
            lacc4[mt] = __builtin_amdgcn_mfma_f32_16x16x32_bf16(pa0, onesf, lacc4[mt], 0, 0, 0);
            lacc4[mt] = __builtin_amdgcn_mfma_f32_16x16x32_bf16(pa1, onesf, lacc4[mt], 0, 0, 0);
            #pragma unroll
            for (int nt2 = 0; nt2 < 4; nt2++) {
                const int vrow = w * 64 + nt2 * 16 + m16;
                bf16x8 bv0 = *(const bf16x8*)&Vts[vrow * 64 + (((0 + quad) ^ (m16 & 7)) * 8)];
                bf16x8 bv1 = *(const bf16x8*)&Vts[vrow * 64 + (((4 + quad) ^ (m16 & 7)) * 8)];
                f32x4 acc = o_acc[mt][nt2];
                acc = __builtin_amdgcn_mfma_f32_16x16x32_bf16(pa0, bv0, acc, 0, 0, 0);
                acc = __builtin_amdgcn_mfma_f32_16x16x32_bf16(pa1, bv1, acc, 0, 0, 0);
                o_acc[mt][nt2] = acc;
            }
        }
        __syncthreads();   // b2: Ps/Vts reads done; Ks write visible

        if (more) {
            #pragma unroll
            for (int p = 0; p < 8; p++)
                *(bf16x8*)&Vts[(p * 32 + w * 8) * 64 + lane * 8] = vreg[p];
        }
    }

    #pragma unroll
    for (int mt = 0; mt < 4; mt++) {
        #pragma unroll
        for (int reg = 0; reg < 4; reg++) {
            const float l = __shfl(lacc4[mt][reg], quad * 16);
            const float invl = 1.0f / l;
            u16* orow = O + (baseRow + q0 + mt * 16 + quad * 4 + reg) * DH + h * 256 + w * 64 + m16;
            #pragma unroll
            for (int nt2 = 0; nt2 < 4; nt2++)
                orow[nt2 * 16] = f2b(gelu_exact(o_acc[mt][nt2][reg] * invl));
        }
    }
}

// ---------------------------------------------------------------------------
extern "C" void kernel_launch(void* const* d_in, const int* in_sizes, int n_in,
                              void* d_out, int out_size, void* d_ws, size_t ws_size,
                              hipStream_t stream)
{
    const float* x   = (const float*)d_in[0];
    const float* Wk  = (const float*)d_in[1];
    const float* bk  = (const float*)d_in[2];
    const float* Wv  = (const float*)d_in[3];
    const float* bv  = (const float*)d_in[4];
    const float* Wf  = (const float*)d_in[5];
    const float* bfb = (const float*)d_in[6];
    float* out = (float*)d_out;

    const int Bsz = 2, S = 2048, DM = 1024, DH = 4096;
    const int M = Bsz * S;  // 4096
    const size_t MB = 1024 * 1024;

    u16* xb   = (u16*)d_ws;                  //  8 MB  [4096][1024] bf16
    u16* Wkt  = xb   + 4 * MB;               //  2 MB  [1024 n][1024 k]
    u16* Wvt  = Wkt  + 1 * MB;               //  8 MB  [4096 n][1024 k]
    u16* Wft  = Wvt  + 4 * MB;               //  8 MB  [1024 n][4096 k]
    u16* Kbuf = Wft  + 4 * MB;               //  8 MB  [4096][1024]
    u16* Vt   = Kbuf + 4 * MB;               // 32 MB  [b][h][256][2048]
    u16* Obuf = Vt   + 16 * MB;              // 32 MB  [4096][4096]

    dim3 blk(256);

    // 0) preprocessing: x -> bf16; all weight transposes in one dispatch
    convert_f2b<<<dim3(M * DM / 1024), blk, 0, stream>>>(x, xb);
    transpose_all<<<dim3(9216), blk, 0, stream>>>(Wk, Wv, Wf, Wkt, Wvt, Wft);

    // 1) fused K + V projections (128x128 tiles, N-space 5120)
    mfma_kv<<<dim3(5120 / 128, M / 128), blk, 0, stream>>>(xb, Wkt, Wvt, bk, bv, Kbuf, Vt);

    // 2) o = gelu(causal_softmax(Q K^T) V)  (bf16, dv-split PV)
    attn_kernel<<<dim3(S / 64, 16, Bsz), blk, 0, stream>>>(x, Kbuf, Vt, Obuf, Bsz, S);

    // 3) out = x + gelu_o @ Wf + bf  (fp32, 128x128 tile)
    mfma_ffn<<<dim3(DM / 128, M / 128), blk, 0, stream>>>(Obuf, Wft, bfb, x, out, M, DM, DH);
}

// Round 14
// 335.469 us; speedup vs baseline: 1.1655x; 1.1655x over previous
//
#include <hip/hip_runtime.h>
#include <math.h>

typedef unsigned short u16;
typedef __attribute__((ext_vector_type(8))) short bf16x8;   // 8 bf16 = 4 VGPRs
typedef __attribute__((ext_vector_type(4))) float f32x4;

__device__ __forceinline__ float b2f(u16 u) {
    union { unsigned int i; float f; } v; v.i = ((unsigned int)u) << 16; return v.f;
}
__device__ __forceinline__ u16 f2b(float f) {
    union { float f; unsigned int i; } v; v.f = f;
    unsigned int r = v.i + 0x7FFFu + ((v.i >> 16) & 1u);   // round-nearest-even
    return (u16)(r >> 16);
}
__device__ __forceinline__ float gelu_exact(float v) {
    return 0.5f * v * (1.0f + erff(v * 0.70710678118654752f));
}

// async global->LDS, 16 B per lane; LDS dest = wave-uniform base + lane*16
__device__ __forceinline__ void load_lds16(const u16* gp, u16* lp) {
    __builtin_amdgcn_global_load_lds(
        (const __attribute__((address_space(1))) void*)gp,
        (__attribute__((address_space(3))) void*)lp,
        16, 0, 0);
}

// ---------------------------------------------------------------------------
// Elementwise fp32 -> bf16 convert (x)
// ---------------------------------------------------------------------------
__global__ __launch_bounds__(256) void convert_f2b(const float* __restrict__ in,
                                                   u16* __restrict__ out) {
    const int idx = blockIdx.x * 256 + threadIdx.x;
    float4 v = ((const float4*)in)[idx];
    ushort4 u; u.x = f2b(v.x); u.y = f2b(v.y); u.z = f2b(v.z); u.w = f2b(v.w);
    ((ushort4*)out)[idx] = u;
}

// ---------------------------------------------------------------------------
// All three weight transposes in ONE dispatch. 32x32 LDS tiles.
// ---------------------------------------------------------------------------
__global__ __launch_bounds__(256) void transpose_all(
    const float* __restrict__ Wk, const float* __restrict__ Wv,
    const float* __restrict__ Wf,
    u16* __restrict__ Wkt, u16* __restrict__ Wvt, u16* __restrict__ Wft)
{
    const int gid = blockIdx.x;
    const float* W; u16* Wt; int N, K, n0, k0;
    if (gid < 1024) {
        W = Wk; Wt = Wkt; N = 1024; K = 1024;
        n0 = (gid & 31) * 32; k0 = (gid >> 5) * 32;
    } else if (gid < 5120) {
        const int g = gid - 1024;
        W = Wv; Wt = Wvt; N = 4096; K = 1024;
        n0 = (g & 127) * 32; k0 = (g >> 7) * 32;
    } else {
        const int g = gid - 5120;
        W = Wf; Wt = Wft; N = 1024; K = 4096;
        n0 = (g & 31) * 32; k0 = (g >> 5) * 32;
    }
    __shared__ float t[32][33];
    const int tid = threadIdx.x;
    const int c = tid & 31, r = tid >> 5;   // 8 rows/pass
    #pragma unroll
    for (int p = 0; p < 4; p++)
        t[r + p * 8][c] = W[(size_t)(k0 + r + p * 8) * N + n0 + c];
    __syncthreads();
    #pragma unroll
    for (int p = 0; p < 4; p++)
        Wt[(size_t)(n0 + r + p * 8) * K + k0 + c] = f2b(t[c][r + p * 8]);
}

// ---------------------------------------------------------------------------
// Fused K+V projection GEMM, 128x128x64 tile. N-space = 5120:
// cols [0,1024)  -> K = x@Wk + bk, bf16 normal store to Kbuf[4096][1024]
// cols [1024,5120) -> V = x@Wv + bv, bf16 TRANSPOSED store to Vt[b][h][dv][s]
// ---------------------------------------------------------------------------
__global__ __launch_bounds__(256) void mfma_kv(
    const u16* __restrict__ A, const u16* __restrict__ Wkt,
    const u16* __restrict__ Wvt, const float* __restrict__ bk,
    const float* __restrict__ bv, u16* __restrict__ Kbuf,
    u16* __restrict__ Vt)
{
    const int K = 1024;
    __shared__ u16 As[128 * 64];   // 16 KB
    __shared__ u16 Bs[128 * 64];   // 16 KB

    const int tid = threadIdx.x;
    const int w = tid >> 6, lane = tid & 63;
    const int m16 = lane & 15, quad = lane >> 4;
    const int wm = w >> 1, wn = w & 1;
    const int row0 = blockIdx.y * 128;
    const int col0g = blockIdx.x * 128;
    const bool isK = (col0g < 1024);
    const u16* Bt = isK ? Wkt : Wvt;
    const int bcol0 = isK ? col0g : col0g - 1024;
    const float* bias = isK ? bk : bv;
    const int lr = lane >> 3, lc = lane & 7;
    const int sw8 = (lc ^ (lr & 7)) * 8;

    f32x4 acc[4][4];
    #pragma unroll
    for (int i = 0; i < 4; i++)
        #pragma unroll
        for (int j = 0; j < 4; j++) acc[i][j] = (f32x4){0.f, 0.f, 0.f, 0.f};

    for (int k0 = 0; k0 < K; k0 += 64) {
        __syncthreads();
        #pragma unroll
        for (int c2 = 0; c2 < 4; c2++)
            load_lds16(A + (size_t)(row0 + c2 * 32 + w * 8 + lr) * K + k0 + sw8,
                       &As[(c2 * 32 + w * 8) * 64]);
        #pragma unroll
        for (int c2 = 0; c2 < 4; c2++)
            load_lds16(Bt + (size_t)(bcol0 + c2 * 32 + w * 8 + lr) * K + k0 + sw8,
                       &Bs[(c2 * 32 + w * 8) * 64]);
        __syncthreads();

        bf16x8 af[4][2], bfr[4][2];
        #pragma unroll
        for (int mt = 0; mt < 4; mt++)
            #pragma unroll
            for (int ks = 0; ks < 2; ks++)
                af[mt][ks] = *(const bf16x8*)&As[(wm * 64 + mt * 16 + m16) * 64 +
                                                 (((ks * 4 + quad) ^ (m16 & 7)) * 8)];
        #pragma unroll
        for (int nt = 0; nt < 4; nt++)
            #pragma unroll
            for (int ks = 0; ks < 2; ks++)
                bfr[nt][ks] = *(const bf16x8*)&Bs[(wn * 64 + nt * 16 + m16) * 64 +
                                                  (((ks * 4 + quad) ^ (m16 & 7)) * 8)];

        #pragma unroll
        for (int ks = 0; ks < 2; ks++)
            #pragma unroll
            for (int mt = 0; mt < 4; mt++)
                #pragma unroll
                for (int nt = 0; nt < 4; nt++)
                    acc[mt][nt] = __builtin_amdgcn_mfma_f32_16x16x32_bf16(af[mt][ks], bfr[nt][ks], acc[mt][nt], 0, 0, 0);
    }

    if (isK) {
        #pragma unroll
        for (int mt = 0; mt < 4; mt++) {
            #pragma unroll
            for (int nt = 0; nt < 4; nt++) {
                const int c = bcol0 + wn * 64 + nt * 16 + m16;
                const float bc = bias[c];
                #pragma unroll
                for (int reg = 0; reg < 4; reg++) {
                    const int r = row0 + wm * 64 + mt * 16 + quad * 4 + reg;
                    Kbuf[(size_t)r * 1024 + c] = f2b(acc[mt][nt][reg] + bc);
                }
            }
        }
    } else {
        #pragma unroll
        for (int mt = 0; mt < 4; mt++) {
            const int r0 = row0 + wm * 64 + mt * 16 + quad * 4;
            const int bb = r0 >> 11, s = r0 & 2047;
            #pragma unroll
            for (int nt = 0; nt < 4; nt++) {
                const int c = bcol0 + wn * 64 + nt * 16 + m16;
                const int h = c >> 8, dv = c & 255;
                const float bc = bias[c];
                ushort4 w4;
                w4.x = f2b(acc[mt][nt][0] + bc);
                w4.y = f2b(acc[mt][nt][1] + bc);
                w4.z = f2b(acc[mt][nt][2] + bc);
                w4.w = f2b(acc[mt][nt][3] + bc);
                *(ushort4*)(Vt + (((size_t)((bb * 16 + h) * 256 + dv)) << 11) + s) = w4;
            }
        }
    }
}

// ---------------------------------------------------------------------------
// FFN GEMM, 64(M) x 128(N) x 64(K) tile (512 blocks -> 2/CU):
// out = gelu_o @ Wft^T + bf + x  (fp32 store)
// ---------------------------------------------------------------------------
__global__ __launch_bounds__(256) void mfma_ffn(
    const u16* __restrict__ A, const u16* __restrict__ Bt,
    const float* __restrict__ bias, const float* __restrict__ resid,
    float* __restrict__ C, int M, int N, int K)
{
    __shared__ u16 As[64 * 64];    //  8 KB
    __shared__ u16 Bs[128 * 64];   // 16 KB

    const int tid = threadIdx.x;
    const int w = tid >> 6, lane = tid & 63;
    const int m16 = lane & 15, quad = lane >> 4;
    const int wm = w >> 1, wn = w & 1;
    const int row0 = blockIdx.y * 64, col0 = blockIdx.x * 128;
    const int lr = lane >> 3, lc = lane & 7;
    const int sw8 = (lc ^ (lr & 7)) * 8;

    f32x4 acc[2][4];
    #pragma unroll
    for (int i = 0; i < 2; i++)
        #pragma unroll
        for (int j = 0; j < 4; j++) acc[i][j] = (f32x4){0.f, 0.f, 0.f, 0.f};

    for (int k0 = 0; k0 < K; k0 += 64) {
        __syncthreads();
        #pragma unroll
        for (int c2 = 0; c2 < 2; c2++)
            load_lds16(A + (size_t)(row0 + c2 * 32 + w * 8 + lr) * K + k0 + sw8,
                       &As[(c2 * 32 + w * 8) * 64]);
        #pragma unroll
        for (int c2 = 0; c2 < 4; c2++)
            load_lds16(Bt + (size_t)(col0 + c2 * 32 + w * 8 + lr) * K + k0 + sw8,
                       &Bs[(c2 * 32 + w * 8) * 64]);
        __syncthreads();

        bf16x8 af[2][2], bfr[4][2];
        #pragma unroll
        for (int mt = 0; mt < 2; mt++)
            #pragma unroll
            for (int ks = 0; ks < 2; ks++)
                af[mt][ks] = *(const bf16x8*)&As[(wm * 32 + mt * 16 + m16) * 64 +
                                                 (((ks * 4 + quad) ^ (m16 & 7)) * 8)];
        #pragma unroll
        for (int nt = 0; nt < 4; nt++)
            #pragma unroll
            for (int ks = 0; ks < 2; ks++)
                bfr[nt][ks] = *(const bf16x8*)&Bs[(wn * 64 + nt * 16 + m16) * 64 +
                                                  (((ks * 4 + quad) ^ (m16 & 7)) * 8)];

        #pragma unroll
        for (int ks = 0; ks < 2; ks++)
            #pragma unroll
            for (int mt = 0; mt < 2; mt++)
                #pragma unroll
                for (int nt = 0; nt < 4; nt++)
                    acc[mt][nt] = __builtin_amdgcn_mfma_f32_16x16x32_bf16(af[mt][ks], bfr[nt][ks], acc[mt][nt], 0, 0, 0);
    }

    #pragma unroll
    for (int mt = 0; mt < 2; mt++) {
        #pragma unroll
        for (int nt = 0; nt < 4; nt++) {
            const int c = col0 + wn * 64 + nt * 16 + m16;
            const float bc = bias[c];
            #pragma unroll
            for (int reg = 0; reg < 4; reg++) {
                const int r = row0 + wm * 32 + mt * 16 + quad * 4 + reg;
                C[(size_t)r * N + c] = acc[mt][nt][reg] + bc + resid[(size_t)r * N + c];
            }
        }
    }
}

// ---------------------------------------------------------------------------
// Flash-style causal attention (R12 compute structure) + XCD-AWARE SWIZZLE:
// all 32 q-tile blocks of one (b,h) get linear ids == same value mod 8, so
// they land on ONE XCD and its L2 keeps that head's Vt (1MB) + K resident.
// q-split QK^T, dv-split PV, max-free softmax, fused GELU, reg-prefetch dbuf.
// ---------------------------------------------------------------------------
__global__ __launch_bounds__(256) void attn_kernel(
    const float* __restrict__ X,    // [B*S, 1024]
    const u16*  __restrict__ Kb,    // [B*S, 1024] bf16
    const u16*  __restrict__ Vt,    // [b][h][256][2048] bf16
    u16* __restrict__ O,            // [B*S, 4096] bf16 (gelu applied)
    int B, int S)
{
    const int DM = 1024, DH = 4096;
    __shared__ u16 Ks[64 * 64];    // 8 KB
    __shared__ u16 Ps[64 * 64];    // 8 KB
    __shared__ u16 Vts[256 * 64];  // 32 KB  (48 KB total)

    const int tid = threadIdx.x;
    const int w = tid >> 6, lane = tid & 63;
    const int m16 = lane & 15, quad = lane >> 4;
    const int lr = lane >> 3, lc = lane & 7;
    const int sw8 = (lc ^ (lr & 7)) * 8;

    // ---- XCD-aware work assignment (lid%8 ~ XCD round-robin heuristic) ----
    const int lid = blockIdx.x + 32 * (blockIdx.y + 16 * blockIdx.z);
    const int xcd = lid & 7, j = lid >> 3;
    const int pr = j >> 5, qtr = j & 31;
    const int h = xcd + 8 * (pr & 1);
    const int b = pr >> 1;
    const int qt = (S / 64 - 1) - qtr;     // big tiles first within each (b,h)
    const int q0 = qt * 64;
    const size_t baseRow = (size_t)b * S;
    const size_t vhead = ((size_t)(b * 16 + h) * 256) << 11;

    bf16x8 aq[2];
    {
        const float* qsrc = X + (baseRow + q0 + w * 16 + m16) * DM + h * 64;
        #pragma unroll
        for (int ks = 0; ks < 2; ks++) {
            float4 v0 = *(const float4*)(qsrc + ks * 32 + quad * 8);
            float4 v1 = *(const float4*)(qsrc + ks * 32 + quad * 8 + 4);
            bf16x8 u;
            u[0] = (short)f2b(v0.x); u[1] = (short)f2b(v0.y); u[2] = (short)f2b(v0.z); u[3] = (short)f2b(v0.w);
            u[4] = (short)f2b(v1.x); u[5] = (short)f2b(v1.y); u[6] = (short)f2b(v1.z); u[7] = (short)f2b(v1.w);
            aq[ks] = u;
        }
    }

    f32x4 o_acc[4][4];
    #pragma unroll
    for (int i = 0; i < 4; i++)
        #pragma unroll
        for (int j2 = 0; j2 < 4; j2++) o_acc[i][j2] = (f32x4){0.f, 0.f, 0.f, 0.f};
    f32x4 lacc4[4];
    #pragma unroll
    for (int i = 0; i < 4; i++) lacc4[i] = (f32x4){0.f, 0.f, 0.f, 0.f};

    bf16x8 onesf;
    {
        const short one = (m16 == 0) ? (short)0x3F80 : (short)0;
        #pragma unroll
        for (int i = 0; i < 8; i++) onesf[i] = one;
    }

    bf16x8 kreg[2], vreg[8];
    #pragma unroll
    for (int p = 0; p < 2; p++)
        kreg[p] = *(const bf16x8*)(Kb + (baseRow + p * 32 + w * 8 + lr) * DM + h * 64 + sw8);
    #pragma unroll
    for (int p = 0; p < 8; p++)
        vreg[p] = *(const bf16x8*)(Vt + vhead + (((size_t)(p * 32 + w * 8 + lr)) << 11) + sw8);
    #pragma unroll
    for (int p = 0; p < 2; p++)
        *(bf16x8*)&Ks[(p * 32 + w * 8) * 64 + lane * 8] = kreg[p];
    #pragma unroll
    for (int p = 0; p < 8; p++)
        *(bf16x8*)&Vts[(p * 32 + w * 8) * 64 + lane * 8] = vreg[p];
    __syncthreads();

    const int nch = qt + 1;
    for (int ch = 0; ch < nch; ch++) {
        const int k0 = ch * 64;
        const bool more = (ch + 1 < nch);

        if (more) {
            const int kn = k0 + 64;
            #pragma unroll
            for (int p = 0; p < 2; p++)
                kreg[p] = *(const bf16x8*)(Kb + (baseRow + kn + p * 32 + w * 8 + lr) * DM + h * 64 + sw8);
            #pragma unroll
            for (int p = 0; p < 8; p++)
                vreg[p] = *(const bf16x8*)(Vt + vhead + (((size_t)(p * 32 + w * 8 + lr)) << 11) + kn + sw8);
        }

        const int qg = q0 + w * 16 + quad * 4;
        #pragma unroll
        for (int nt = 0; nt < 4; nt++) {
            f32x4 acc = (f32x4){0.f, 0.f, 0.f, 0.f};
            #pragma unroll
            for (int ks = 0; ks < 2; ks++) {
                bf16x8 bk8 = *(const bf16x8*)&Ks[(nt * 16 + m16) * 64 + (((ks * 4 + quad) ^ (m16 & 7)) * 8)];
                acc = __builtin_amdgcn_mfma_f32_16x16x32_bf16(aq[ks], bk8, acc, 0, 0, 0);
            }
            const int kg = k0 + nt * 16 + m16;
            #pragma unroll
            for (int reg = 0; reg < 4; reg++) {
                const float p = (kg <= qg + reg) ? __expf(acc[reg] - 20.f) : 0.f;
                const int srow = w * 16 + quad * 4 + reg;
                Ps[srow * 64 + (((nt * 2 + (m16 >> 3)) ^ (srow & 7)) * 8) + (m16 & 7)] = f2b(p);
            }
        }
        __syncthreads();   // b1: Ps visible; Ks reads done

        if (more) {
            #pragma unroll
            for (int p = 0; p < 2; p++)
                *(bf16x8*)&Ks[(p * 32 + w * 8) * 64 + lane * 8] = kreg[p];
        }

        #pragma unroll
        for (int mt = 0; mt < 4; mt++) {
            bf16x8 pa0 = *(const bf16x8*)&Ps[(mt * 16 + m16) * 64 + (((0 + quad) ^ (m16 & 7)) * 8)];
            bf16x8 pa1 = *(const bf16x8*)&Ps[(mt * 16 + m16) * 64 + (((4 + quad) ^ (m16 & 7)) * 8)];
            lacc4[mt] = __builtin_amdgcn_mfma_f32_16x16x32_bf16(pa0, onesf, lacc4[mt], 0, 0, 0);
            lacc4[mt] = __builtin_amdgcn_mfma_f32_16x16x32_bf16(pa1, onesf, lacc4[mt], 0, 0, 0);
            #pragma unroll
            for (int nt2 = 0; nt2 < 4; nt2++) {
                const int vrow = w * 64 + nt2 * 16 + m16;
                bf16x8 bv0 = *(const bf16x8*)&Vts[vrow * 64 + (((0 + quad) ^ (m16 & 7)) * 8)];
                bf16x8 bv1 = *(const bf16x8*)&Vts[vrow * 64 + (((4 + quad) ^ (m16 & 7)) * 8)];
                f32x4 acc = o_acc[mt][nt2];
                acc = __builtin_amdgcn_mfma_f32_16x16x32_bf16(pa0, bv0, acc, 0, 0, 0);
                acc = __builtin_amdgcn_mfma_f32_16x16x32_bf16(pa1, bv1, acc, 0, 0, 0);
                o_acc[mt][nt2] = acc;
            }
        }
        __syncthreads();   // b2: Ps/Vts reads done; Ks write visible

        if (more) {
            #pragma unroll
            for (int p = 0; p < 8; p++)
                *(bf16x8*)&Vts[(p * 32 + w * 8) * 64 + lane * 8] = vreg[p];
        }
    }

    #pragma unroll
    for (int mt = 0; mt < 4; mt++) {
        #pragma unroll
        for (int reg = 0; reg < 4; reg++) {
            const float l = __shfl(lacc4[mt][reg], quad * 16);
            const float invl = 1.0f / l;
            u16* orow = O + (baseRow + q0 + mt * 16 + quad * 4 + reg) * DH + h * 256 + w * 64 + m16;
            #pragma unroll
            for (int nt2 = 0; nt2 < 4; nt2++)
                orow[nt2 * 16] = f2b(gelu_exact(o_acc[mt][nt2][reg] * invl));
        }
    }
}

// ---------------------------------------------------------------------------
extern "C" void kernel_launch(void* const* d_in, const int* in_sizes, int n_in,
                              void* d_out, int out_size, void* d_ws, size_t ws_size,
                              hipStream_t stream)
{
    const float* x   = (const float*)d_in[0];
    const float* Wk  = (const float*)d_in[1];
    const float* bk  = (const float*)d_in[2];
    const float* Wv  = (const float*)d_in[3];
    const float* bv  = (const float*)d_in[4];
    const float* Wf  = (const float*)d_in[5];
    const float* bfb = (const float*)d_in[6];
    float* out = (float*)d_out;

    const int Bsz = 2, S = 2048, DM = 1024, DH = 4096;
    const int M = Bsz * S;  // 4096
    const size_t MB = 1024 * 1024;

    u16* xb   = (u16*)d_ws;                  //  8 MB  [4096][1024] bf16
    u16* Wkt  = xb   + 4 * MB;               //  2 MB  [1024 n][1024 k]
    u16* Wvt  = Wkt  + 1 * MB;               //  8 MB  [4096 n][1024 k]
    u16* Wft  = Wvt  + 4 * MB;               //  8 MB  [1024 n][4096 k]
    u16* Kbuf = Wft  + 4 * MB;               //  8 MB  [4096][1024]
    u16* Vt   = Kbuf + 4 * MB;               // 32 MB  [b][h][256][2048]
    u16* Obuf = Vt   + 16 * MB;              // 32 MB  [4096][4096]

    dim3 blk(256);

    // 0) preprocessing: x -> bf16; all weight transposes in one dispatch
    convert_f2b<<<dim3(M * DM / 1024), blk, 0, stream>>>(x, xb);
    transpose_all<<<dim3(9216), blk, 0, stream>>>(Wk, Wv, Wf, Wkt, Wvt, Wft);

    // 1) fused K + V projections (128x128 tiles, N-space 5120)
    mfma_kv<<<dim3(5120 / 128, M / 128), blk, 0, stream>>>(xb, Wkt, Wvt, bk, bv, Kbuf, Vt);

    // 2) o = gelu(causal_softmax(Q K^T) V)  (bf16, dv-split PV, XCD swizzle)
    attn_kernel<<<dim3(S / 64, 16, Bsz), blk, 0, stream>>>(x, Kbuf, Vt, Obuf, Bsz, S);

    // 3) out = x + gelu_o @ Wf + bf  (fp32, 64x128 tile, 512 blocks)
    mfma_ffn<<<dim3(DM / 128, M / 64), blk, 0, stream>>>(Obuf, Wft, bfb, x, out, M, DM, DH);
}